// Round 1
// 101.795 us; speedup vs baseline: 1.0038x; 1.0038x over previous
//
#include <hip/hip_runtime.h>

// ShiftLocalAttention2d: 7x7 neighborhood attention, B=4, C=256 (8 heads x 32),
// H=W=48. fp32 in/out, fp32 accumulate. K/V staged in LDS as f16.
//
// R5: main-loop VALU diet v2.
//  - rx loop is 7 steps (pad lane removed): -12.5% main-loop work.
//  - row validity hoisted to a uniform `continue` (qy uniform per wave);
//    column validity folded into one v_mul via per-lane float mask cmf[7]
//    (replaces v_and+v_cmp+v_cndmask per neighbor).
//  - log2e folded into the Q pre-scale; raw exp2 (saves the v_mul inside
//    __expf). Algebraically identical to exp(score).
//  - staging uses CLAMPED halo coords (no branch, no zero-fill): OOB
//    neighbors are exactly zeroed by the mask multiply (p = pe * 0.0f).
//  - Q loads hoisted above staging so they overlap the halo loads.
// lane = part(4) x qx(16); wave = one query row; 16x6 tile, 3 blocks/CU.

#define H_IMG 48
#define W_IMG 48
#define DHEAD 32
#define NH    8
#define RAD   3
#define TW    16
#define TH    6
#define NPART 4
#define CPL   8                      // channels per lane
#define HALO_W  (TW + 2*RAD)         // 22
#define HALO_H  (TH + 2*RAD)         // 12
#define HALO_PX (HALO_W * HALO_H)    // 264
#define CSTR    40                   // shorts per pixel (80B; 16B-aligned chunks)
#define PLANE   (H_IMG * W_IMG)      // 2304
#define NTHREADS (NPART * TW * TH)   // 384

typedef _Float16 half_t;
typedef half_t half2_t __attribute__((ext_vector_type(2)));

// in-quad butterfly adds via DPP quad_perm (VALU pipe, not LDS)
__device__ __forceinline__ float dppadd1(float x) {   // + lane^1
  int y = __builtin_amdgcn_update_dpp(0, __float_as_int(x), 0xB1, 0xF, 0xF, true);
  return x + __int_as_float(y);
}
__device__ __forceinline__ float dppadd2(float x) {   // + lane^2
  int y = __builtin_amdgcn_update_dpp(0, __float_as_int(x), 0x4E, 0xF, 0xF, true);
  return x + __int_as_float(y);
}

// raw v_exp_f32 (2^x). Guarded: falls back to __expf(x*ln2) if builtin absent.
#if defined(__has_builtin)
#if __has_builtin(__builtin_amdgcn_exp2f)
#define EXP2F(x) __builtin_amdgcn_exp2f(x)
#endif
#endif
#ifndef EXP2F
#define EXP2F(x) __expf(0.6931471805599453f * (x))
#endif

__global__ __launch_bounds__(NTHREADS, 4)
void natten_f32_kernel(const float* __restrict__ q,
                       const float* __restrict__ k,
                       const float* __restrict__ v,
                       float* __restrict__ out) {
  __shared__ __align__(16) unsigned short kl[HALO_PX * CSTR];
  __shared__ __align__(16) unsigned short vl[HALO_PX * CSTR];

  const int part = threadIdx.x;           // 0..3  (channel quarter)
  const int qx   = threadIdx.y;           // 0..15
  const int qy   = threadIdx.z;           // 0..5  (wave index)
  const int tid  = part + NPART * qx + NPART * TW * qy;
  const int x0   = blockIdx.x * TW;
  const int y0   = blockIdx.y * TH;
  const size_t cbase = (size_t)blockIdx.z * DHEAD * PLANE;

  // ---- This lane's 8 query channels, pre-scaled by (1/sqrt(32))*log2(e),
  //      packed f16x2. Issued FIRST so they overlap the halo staging. ----
  const int gqx = x0 + qx, gqy = y0 + qy;
  const float S = 0.17677669529663687f * 1.4426950408889634f;
  const size_t qoff = cbase + (size_t)gqy * W_IMG + gqx;
  half2_t qp[4];
#pragma unroll
  for (int j = 0; j < 4; ++j) {
    qp[j].x = (half_t)(q[qoff + (size_t)(part * CPL + 2 * j) * PLANE] * S);
    qp[j].y = (half_t)(q[qoff + (size_t)(part * CPL + 2 * j + 1) * PLANE] * S);
  }

  // ---- per-lane column mask as float {0,1}; ry-invariant ----
  float cmf[7];
#pragma unroll
  for (int rx = 0; rx < 7; ++rx) {
    const int gx = gqx + rx - RAD;
    cmf[rx] = ((unsigned)gx < (unsigned)W_IMG) ? 1.0f : 0.0f;
  }

  // ---- Stage K/V halo as packed f16, one b128 (8ch) per (pixel,chunk).
  //      CLAMPED coords: OOB pixels hold valid-but-wrong data; their score
  //      is multiplied by cmf==0 (or the row is skipped), so never used. ----
  for (int i = tid; i < HALO_PX * 4; i += NTHREADS) {
    const int pix = i >> 2, chunk = i & 3;
    const int hy = pix / HALO_W;
    const int hx = pix - hy * HALO_W;
    int gy = y0 - RAD + hy;
    int gx = x0 - RAD + hx;
    gy = gy < 0 ? 0 : (gy > H_IMG - 1 ? H_IMG - 1 : gy);
    gx = gx < 0 ? 0 : (gx > W_IMG - 1 ? W_IMG - 1 : gx);
    const size_t g = cbase + (size_t)(chunk * CPL) * PLANE + (size_t)gy * W_IMG + gx;
    const float* kb = k + g;
    const float* vb = v + g;
    union { half2_t h2[4]; uint4 u; } kk, vv;
#pragma unroll
    for (int j = 0; j < 4; ++j) {
      half2_t a, b;
      a.x = (half_t)kb[(2 * j) * PLANE];  a.y = (half_t)kb[(2 * j + 1) * PLANE];
      b.x = (half_t)vb[(2 * j) * PLANE];  b.y = (half_t)vb[(2 * j + 1) * PLANE];
      kk.h2[j] = a;  vv.h2[j] = b;
    }
    *(uint4*)&kl[pix * CSTR + chunk * CPL] = kk.u;
    *(uint4*)&vl[pix * CSTR + chunk * CPL] = vv.u;
  }

  __syncthreads();

  float den = 0.0f;
  float o[CPL];
#pragma unroll
  for (int j = 0; j < CPL; ++j) o[j] = 0.0f;

  for (int ry = 0; ry < 2 * RAD + 1; ++ry) {
    const int gy = gqy + ry - RAD;
    if ((unsigned)gy >= (unsigned)H_IMG) continue;   // uniform per wave
    const int base = ((qy + ry) * HALO_W + qx) * CSTR + part * CPL;
    const unsigned short* kb = &kl[base];
    const unsigned short* vb = &vl[base];
#pragma unroll
    for (int rx = 0; rx < 7; ++rx) {
      union { uint4 u; half2_t h[4]; } kw, vw;
      kw.u = *(const uint4*)(kb + rx * CSTR);
      vw.u = *(const uint4*)(vb + rx * CSTR);
      float acc = __builtin_amdgcn_fdot2(qp[0], kw.h[0], 0.0f, false);
      acc = __builtin_amdgcn_fdot2(qp[1], kw.h[1], acc, false);
      acc = __builtin_amdgcn_fdot2(qp[2], kw.h[2], acc, false);
      acc = __builtin_amdgcn_fdot2(qp[3], kw.h[3], acc, false);
      acc = dppadd1(acc);                  // parts {0,1},{2,3}
      acc = dppadd2(acc);                  // full 32-ch dot in all 4 part-lanes
      const float p = EXP2F(acc) * cmf[rx];  // mask folded into one v_mul
      den += p;
      o[0] += p * (float)vw.h[0].x;  o[1] += p * (float)vw.h[0].y;
      o[2] += p * (float)vw.h[1].x;  o[3] += p * (float)vw.h[1].y;
      o[4] += p * (float)vw.h[2].x;  o[5] += p * (float)vw.h[2].y;
      o[6] += p * (float)vw.h[3].x;  o[7] += p * (float)vw.h[3].y;
    }
  }

  const float rden = 1.0f / den;           // den >= exp(center score) > 0
#pragma unroll
  for (int j = 0; j < CPL; ++j)
    out[qoff + (size_t)(part * CPL + j) * PLANE] = o[j] * rden;
}

extern "C" void kernel_launch(void* const* d_in, const int* in_sizes, int n_in,
                              void* d_out, int out_size, void* d_ws, size_t ws_size,
                              hipStream_t stream) {
  const float* q = (const float*)d_in[0];
  const float* k = (const float*)d_in[1];
  const float* v = (const float*)d_in[2];
  float* out = (float*)d_out;

  dim3 grid(W_IMG / TW, H_IMG / TH, 4 * NH);   // (3, 8, 32) = 768 blocks
  dim3 block(NPART, TW, TH);                    // 384 threads = 6 waves
  hipLaunchKernelGGL(natten_f32_kernel, grid, block, 0, stream, q, k, v, out);
}